// Round 1
// baseline (1166.412 us; speedup 1.0000x reference)
//
#include <hip/hip_runtime.h>

#define HDIM 4096
#define NROWS 16384      // B*S = 4*4096
#define TPB 256
#define EPS_RMS 1e-6f

__device__ __forceinline__ float wave_reduce_sum(float v) {
    #pragma unroll
    for (int off = 32; off > 0; off >>= 1)
        v += __shfl_down(v, off, 64);
    return v;
}
__device__ __forceinline__ float wave_reduce_max(float v) {
    #pragma unroll
    for (int off = 32; off > 0; off >>= 1)
        v = fmaxf(v, __shfl_down(v, off, 64));
    return v;
}

// Pass 1: x = x1 + x2 (store), per-row inv_rms (store to ws), global abs-max of
// normalized output via atomicMax on uint bits (valid: all values >= 0).
__global__ __launch_bounds__(TPB) void pass1_kernel(
    const float4* __restrict__ x1, const float4* __restrict__ x2,
    const float4* __restrict__ gamma, float4* __restrict__ xout,
    float* __restrict__ inv_rms, unsigned int* __restrict__ gmax) {
    const int row = blockIdx.x;
    const int t   = threadIdx.x;
    const size_t rowbase = (size_t)row * (HDIM / 4);

    float ss = 0.f;   // sum of squares of x
    float gm = 0.f;   // max |x * gamma| (inv_rms applied after reduce)
    #pragma unroll
    for (int k = 0; k < 4; ++k) {
        const int idx = t + k * TPB;
        float4 a = x1[rowbase + idx];
        float4 b = x2[rowbase + idx];
        float4 v;
        v.x = a.x + b.x; v.y = a.y + b.y; v.z = a.z + b.z; v.w = a.w + b.w;
        xout[rowbase + idx] = v;
        ss += v.x * v.x + v.y * v.y + v.z * v.z + v.w * v.w;
        float4 g = gamma[idx];
        gm = fmaxf(gm, fabsf(v.x * g.x));
        gm = fmaxf(gm, fabsf(v.y * g.y));
        gm = fmaxf(gm, fabsf(v.z * g.z));
        gm = fmaxf(gm, fabsf(v.w * g.w));
    }

    __shared__ float red_s[4];
    __shared__ float red_m[4];
    const int wave = t >> 6, lane = t & 63;
    float wsum = wave_reduce_sum(ss);
    float wmax = wave_reduce_max(gm);
    if (lane == 0) { red_s[wave] = wsum; red_m[wave] = wmax; }
    __syncthreads();
    if (t == 0) {
        float tot = (red_s[0] + red_s[1]) + (red_s[2] + red_s[3]);
        float inv = rsqrtf(tot * (1.0f / HDIM) + EPS_RMS);
        inv_rms[row] = inv;
        float m = fmaxf(fmaxf(red_m[0], red_m[1]), fmaxf(red_m[2], red_m[3])) * inv;
        atomicMax(gmax, __float_as_uint(m));  // device-scope; floats >=0 order as uints
    }
}

// Pass 2: recompute out = x * inv_rms * gamma, quantize with round-half-even,
// write y1, y2 (as fp32 -- harness output dtype) and the two scale scalars.
__global__ __launch_bounds__(TPB) void pass2_kernel(
    const float4* __restrict__ x, const float4* __restrict__ gamma,
    const float* __restrict__ inv_rms, const unsigned int* __restrict__ gmax,
    float4* __restrict__ y1, float4* __restrict__ y2,
    float* __restrict__ scales) {
    const int row = blockIdx.x;
    const int t   = threadIdx.x;
    const float inv  = inv_rms[row];
    const float maxv = __uint_as_float(*gmax);
    const float qs   = 127.0f / maxv;     // multiply instead of divide by scale
    const float c    = inv * qs;          // fold per-row inv_rms into quant factor
    if (row == 0 && t == 0) {
        float scale = maxv * (1.0f / 127.0f);
        scales[0] = scale;
        scales[1] = scale;
    }
    const size_t rowbase = (size_t)row * (HDIM / 4);
    #pragma unroll
    for (int k = 0; k < 4; ++k) {
        const int idx = t + k * TPB;
        float4 v = x[rowbase + idx];
        float4 g = gamma[idx];
        float4 q;
        q.x = fminf(fmaxf(rintf(v.x * g.x * c), -128.f), 127.f);
        q.y = fminf(fmaxf(rintf(v.y * g.y * c), -128.f), 127.f);
        q.z = fminf(fmaxf(rintf(v.z * g.z * c), -128.f), 127.f);
        q.w = fminf(fmaxf(rintf(v.w * g.w * c), -128.f), 127.f);
        y1[rowbase + idx] = q;
        y2[rowbase + idx] = q;
    }
}

extern "C" void kernel_launch(void* const* d_in, const int* in_sizes, int n_in,
                              void* d_out, int out_size, void* d_ws, size_t ws_size,
                              hipStream_t stream) {
    const float* x1    = (const float*)d_in[0];
    const float* x2    = (const float*)d_in[1];
    const float* gamma = (const float*)d_in[2];
    // d_in[3], d_in[4] (smooth_scale1/2) are unused by the reference computation.

    const size_t N = (size_t)NROWS * HDIM;  // 67,108,864
    float* out    = (float*)d_out;
    float* y1     = out;            // [0, N)
    float* y2     = out + N;        // [N, 2N)
    float* xo     = out + 2 * N;    // [2N, 3N)
    float* scales = out + 3 * N;    // scale1, scale2

    unsigned int* gmax = (unsigned int*)d_ws;
    float* inv_rms     = (float*)((char*)d_ws + 16);   // NROWS floats = 64 KiB

    hipMemsetAsync(d_ws, 0, 16, stream);  // zero the abs-max slot

    pass1_kernel<<<NROWS, TPB, 0, stream>>>(
        (const float4*)x1, (const float4*)x2, (const float4*)gamma,
        (float4*)xo, inv_rms, gmax);

    pass2_kernel<<<NROWS, TPB, 0, stream>>>(
        (const float4*)xo, (const float4*)gamma, inv_rms, gmax,
        (float4*)y1, (float4*)y2, scales);
}